// Round 1
// baseline (89.718 us; speedup 1.0000x reference)
//
#include <hip/hip_runtime.h>
#include <cmath>

#ifndef M_PI
#define M_PI 3.14159265358979323846
#endif

constexpr int T_LEN  = 320000;
constexpr int B_ROWS = 64;
constexpr int CHUNK  = 800;                 // samples per thread (main region)
constexpr int NCHUNK = T_LEN / CHUNK;       // 400 chunks per row
constexpr int WARM   = 128;                 // warm-up samples (pole decay 0.87^128 ~ 2e-8)

__global__ __launch_bounds__(256) void biquad_chunked_kernel(
    const float* __restrict__ x, float* __restrict__ y,
    float b0, float b1, float b2, float a1, float a2) {
  int tid = blockIdx.x * blockDim.x + threadIdx.x;
  if (tid >= B_ROWS * NCHUNK) return;
  int row   = tid / NCHUNK;
  int chunk = tid % NCHUNK;

  const float* xr = x + (size_t)row * T_LEN;
  float*       yr = y + (size_t)row * T_LEN;
  int s = chunk * CHUNK;

  float x1 = 0.f, x2 = 0.f, y1 = 0.f, y2 = 0.f;

  // Restructured recurrence: t has no dependence on y; u depends on y2 (ready
  // one step early); only the final FMA is on the loop-carried critical path.
  auto step = [&](float xn) -> float {
    float t  = fmaf(b2, x2, fmaf(b1, x1, b0 * xn));
    float u  = fmaf(-a2, y2, t);
    float yn = fmaf(-a1, y1, u);
    x2 = x1; x1 = xn;
    y2 = y1; y1 = yn;
    return yn;
  };

  if (chunk > 0) {
    // Warm-up region: run recurrence over preceding WARM samples, no stores.
    const float4* xw = reinterpret_cast<const float4*>(xr + s - WARM);
#pragma unroll 4
    for (int i = 0; i < WARM / 4; ++i) {
      float4 v = xw[i];
      step(v.x); step(v.y); step(v.z); step(v.w);
    }
  }

  const float4* xm = reinterpret_cast<const float4*>(xr + s);
  float4*       ym = reinterpret_cast<float4*>(yr + s);
#pragma unroll 2
  for (int i = 0; i < CHUNK / 4; ++i) {
    float4 v = xm[i];
    float4 o;
    o.x = step(v.x); o.y = step(v.y); o.z = step(v.z); o.w = step(v.w);
    ym[i] = o;
  }
}

extern "C" void kernel_launch(void* const* d_in, const int* in_sizes, int n_in,
                              void* d_out, int out_size, void* d_ws, size_t ws_size,
                              hipStream_t stream) {
  const float* x = (const float*)d_in[0];
  float*       y = (float*)d_out;

  // Coefficients in double (matches Python-float math), cast to fp32 like the
  // reference's jnp.asarray(..., float32).
  const double sample_rate = 16000.0, cutoff = 7500.0, Q = 0.707;
  double w0    = 2.0 * M_PI * cutoff / sample_rate;
  double alpha = sin(w0) / (2.0 * Q);
  double cw    = cos(w0);
  double a0    = 1.0 + alpha;
  float b0 = (float)(((1.0 - cw) * 0.5) / a0);
  float b1 = (float)((1.0 - cw) / a0);
  float b2 = b0;
  float a1 = (float)((-2.0 * cw) / a0);
  float a2 = (float)((1.0 - alpha) / a0);

  int total = B_ROWS * NCHUNK;  // 25600 threads
  dim3 block(256);
  dim3 grid((total + block.x - 1) / block.x);  // 100 blocks
  hipLaunchKernelGGL(biquad_chunked_kernel, grid, block, 0, stream,
                     x, y, b0, b1, b2, a1, a2);
}

// Round 2
// 59.400 us; speedup vs baseline: 1.5104x; 1.5104x over previous
//
#include <hip/hip_runtime.h>
#include <cmath>

#ifndef M_PI
#define M_PI 3.14159265358979323846
#endif

constexpr int T_LEN  = 320000;
constexpr int B_ROWS = 64;
constexpr int CHUNK  = 64;                  // samples per thread (main region)
constexpr int NCHUNK = T_LEN / CHUNK;       // 5000 chunks per row
constexpr int WARM   = 64;                  // pole decay 0.8704^64 = 1.4e-4

__global__ __launch_bounds__(256) void biquad_chunked_kernel(
    const float* __restrict__ x, float* __restrict__ y,
    float b0, float b1, float b2, float a1, float a2) {
  int chunk = blockIdx.x * blockDim.x + threadIdx.x;  // chunk within row
  int row   = blockIdx.y;
  if (chunk >= NCHUNK) return;

  const float* xr = x + (size_t)row * T_LEN;
  float*       yr = y + (size_t)row * T_LEN;
  int s = chunk * CHUNK;

  float x1 = 0.f, x2 = 0.f, y1 = 0.f, y2 = 0.f;

  // Restructured recurrence: only the final FMA is on the loop-carried
  // critical path (u depends on y2, ready one step early).
  auto step = [&](float xn) -> float {
    float t  = fmaf(b2, x2, fmaf(b1, x1, b0 * xn));
    float u  = fmaf(-a2, y2, t);
    float yn = fmaf(-a1, y1, u);
    x2 = x1; x1 = xn;
    y2 = y1; y1 = yn;
    return yn;
  };

  if (chunk > 0) {
    // Warm-up region (= previous chunk, so these reads are L2-resident for
    // the thread that owns it as a main region). Fully unrolled: 16
    // independent float4 loads issued in a batch.
    const float4* xw = reinterpret_cast<const float4*>(xr + s - WARM);
#pragma unroll
    for (int i = 0; i < WARM / 4; ++i) {
      float4 v = xw[i];
      step(v.x); step(v.y); step(v.z); step(v.w);
    }
  }

  const float4* xm = reinterpret_cast<const float4*>(xr + s);
  float4*       ym = reinterpret_cast<float4*>(yr + s);
#pragma unroll
  for (int i = 0; i < CHUNK / 4; ++i) {
    float4 v = xm[i];
    float4 o;
    o.x = step(v.x); o.y = step(v.y); o.z = step(v.z); o.w = step(v.w);
    ym[i] = o;
  }
}

extern "C" void kernel_launch(void* const* d_in, const int* in_sizes, int n_in,
                              void* d_out, int out_size, void* d_ws, size_t ws_size,
                              hipStream_t stream) {
  const float* x = (const float*)d_in[0];
  float*       y = (float*)d_out;

  // Coefficients in double (matches Python-float math), cast to fp32 like the
  // reference's jnp.asarray(..., float32).
  const double sample_rate = 16000.0, cutoff = 7500.0, Q = 0.707;
  double w0    = 2.0 * M_PI * cutoff / sample_rate;
  double alpha = sin(w0) / (2.0 * Q);
  double cw    = cos(w0);
  double a0    = 1.0 + alpha;
  float b0 = (float)(((1.0 - cw) * 0.5) / a0);
  float b1 = (float)((1.0 - cw) / a0);
  float b2 = b0;
  float a1 = (float)((-2.0 * cw) / a0);
  float a2 = (float)((1.0 - alpha) / a0);

  // 5000 chunks/row -> 20 blocks of 256 in x; 64 rows in y.
  dim3 block(256);
  dim3 grid((NCHUNK + block.x - 1) / block.x, B_ROWS);
  hipLaunchKernelGGL(biquad_chunked_kernel, grid, block, 0, stream,
                     x, y, b0, b1, b2, a1, a2);
}

// Round 4
// 55.911 us; speedup vs baseline: 1.6047x; 1.0624x over previous
//
#include <hip/hip_runtime.h>
#include <cmath>

#ifndef M_PI
#define M_PI 3.14159265358979323846
#endif

constexpr int T_LEN  = 320000;
constexpr int B_ROWS = 64;
constexpr int CHUNK  = 32;                  // samples per thread (main region)
constexpr int NCHUNK = T_LEN / CHUNK;       // 10000 chunks per row
constexpr int WARM   = 64;                  // pole decay 0.8704^64 ~ 1.4e-4

__global__ __launch_bounds__(256, 4) void biquad_chunked_kernel(
    const float* __restrict__ x, float* __restrict__ y,
    float b0, float b1, float b2, float a1, float a2) {
  int chunk = blockIdx.x * blockDim.x + threadIdx.x;  // chunk within row
  int row   = blockIdx.y;
  if (chunk >= NCHUNK) return;

  const float* xr = x + (size_t)row * T_LEN;
  float*       yr = y + (size_t)row * T_LEN;
  int s = chunk * CHUNK;

  // Warm-up base, clamped to row start. chunk==1 warms from 0 (its EXACT
  // full history, 32 samples); chunk>=2 uses the full 64-sample warm-up.
  int bs = (chunk >= 2) ? (s - WARM) : 0;

  // ---- Issue ALL loads up front: 16 warm + 8 main float4 in flight. ----
  float4 w[16];
  float4 m[8];
  if (chunk >= 1) {
    const float4* xw = reinterpret_cast<const float4*>(xr + bs);
#pragma unroll
    for (int i = 0; i < WARM / 4; ++i) w[i] = xw[i];   // always in-bounds
  }
  const float4* xm = reinterpret_cast<const float4*>(xr + s);
#pragma unroll
  for (int i = 0; i < CHUNK / 4; ++i) m[i] = xm[i];

  float x1 = 0.f, x2 = 0.f, y1 = 0.f, y2 = 0.f;

  // Restructured recurrence: only the final FMA is on the loop-carried
  // critical path (u depends on y2, ready one step early).
  auto step = [&](float xn) -> float {
    float t  = fmaf(b2, x2, fmaf(b1, x1, b0 * xn));
    float u  = fmaf(-a2, y2, t);
    float yn = fmaf(-a1, y1, u);
    x2 = x1; x1 = xn;
    y2 = y1; y1 = yn;
    return yn;
  };

  if (chunk >= 2) {
#pragma unroll
    for (int i = 0; i < WARM / 4; ++i) {
      step(w[i].x); step(w[i].y); step(w[i].z); step(w[i].w);
    }
  } else if (chunk == 1) {
    // Warm region is [0, 32) = w[0..7] (exact history).
#pragma unroll
    for (int i = 0; i < 8; ++i) {
      step(w[i].x); step(w[i].y); step(w[i].z); step(w[i].w);
    }
  }

#pragma unroll
  for (int i = 0; i < CHUNK / 4; ++i) {
    float4 v = m[i];
    float4 o;
    o.x = step(v.x); o.y = step(v.y); o.z = step(v.z); o.w = step(v.w);
    m[i] = o;
  }

  float4* ym = reinterpret_cast<float4*>(yr + s);
#pragma unroll
  for (int i = 0; i < CHUNK / 4; ++i) ym[i] = m[i];
}

extern "C" void kernel_launch(void* const* d_in, const int* in_sizes, int n_in,
                              void* d_out, int out_size, void* d_ws, size_t ws_size,
                              hipStream_t stream) {
  const float* x = (const float*)d_in[0];
  float*       y = (float*)d_out;

  // Coefficients in double (matches Python-float math), cast to fp32 like the
  // reference's jnp.asarray(..., float32).
  const double sample_rate = 16000.0, cutoff = 7500.0, Q = 0.707;
  double w0    = 2.0 * M_PI * cutoff / sample_rate;
  double alpha = sin(w0) / (2.0 * Q);
  double cw    = cos(w0);
  double a0    = 1.0 + alpha;
  float b0 = (float)(((1.0 - cw) * 0.5) / a0);
  float b1 = (float)((1.0 - cw) / a0);
  float b2 = b0;
  float a1 = (float)((-2.0 * cw) / a0);
  float a2 = (float)((1.0 - alpha) / a0);

  // 10000 chunks/row -> 40 blocks of 256 in x; 64 rows in y.
  dim3 block(256);
  dim3 grid((NCHUNK + block.x - 1) / block.x, B_ROWS);
  hipLaunchKernelGGL(biquad_chunked_kernel, grid, block, 0, stream,
                     x, y, b0, b1, b2, a1, a2);
}

// Round 5
// 36.321 us; speedup vs baseline: 2.4702x; 1.5394x over previous
//
#include <hip/hip_runtime.h>
#include <cmath>

#ifndef M_PI
#define M_PI 3.14159265358979323846
#endif

constexpr int T_LEN  = 320000;
constexpr int B_ROWS = 64;
constexpr int CHUNK  = 32;                       // samples per thread
constexpr int WARM   = 64;                       // pole decay 0.8704^64 ~ 1.4e-4
constexpr int NCHUNK = T_LEN / CHUNK;            // 10000 chunks per row
constexpr int BLK_CHUNKS = 256;                  // chunks per block
constexpr int BLK_SPAN   = BLK_CHUNKS * CHUNK;   // 8192 samples per block
constexpr int TILE_WORDS = BLK_SPAN + WARM;      // 8256 floats = 33 KB LDS

// Word-level XOR swizzle: per-thread stride-32 reads -> 2 lanes/bank (free);
// float4 staging writes -> ~2 lanes/bank. Bijective within 32-word stripes.
__device__ __forceinline__ int swz(int W) { return W ^ ((W >> 5) & 31); }

__global__ __launch_bounds__(256, 4) void biquad_lds_kernel(
    const float* __restrict__ x, float* __restrict__ y,
    float b0, float b1, float b2, float a1, float a2) {
  const int b   = blockIdx.x;
  const int row = blockIdx.y;
  const int t   = threadIdx.x;

  const int S       = b * BLK_SPAN;                       // row-span start
  const int nchunks = min(BLK_CHUNKS, (T_LEN - S) / CHUNK);  // 256, or 16 (tail)
  const int words   = nchunks * CHUNK;

  const float* xr = x + (size_t)row * T_LEN;
  float*       yr = y + (size_t)row * T_LEN;

  __shared__ float lds[TILE_WORDS];

  // ---- Stage [S-WARM, S+words) into LDS: coalesced float4 reads, swizzled
  // scalar LDS writes. Block 0 zero-fills the warm region (so every thread
  // runs a uniform warm-up; zeros from zero state stay zero => exact).
  if (b == 0) {
    if (t < WARM / 4) {
      int W = t * 4;
      lds[swz(W)] = 0.f; lds[swz(W+1)] = 0.f; lds[swz(W+2)] = 0.f; lds[swz(W+3)] = 0.f;
    }
    const float4* src = reinterpret_cast<const float4*>(xr);
    const int nf4 = words / 4;
    for (int i = t; i < nf4; i += 256) {
      float4 v = src[i];
      int W = WARM + i * 4;
      lds[swz(W)] = v.x; lds[swz(W+1)] = v.y; lds[swz(W+2)] = v.z; lds[swz(W+3)] = v.w;
    }
  } else {
    const float4* src = reinterpret_cast<const float4*>(xr + S - WARM);
    const int nf4 = (words + WARM) / 4;
    for (int i = t; i < nf4; i += 256) {
      float4 v = src[i];
      int W = i * 4;
      lds[swz(W)] = v.x; lds[swz(W+1)] = v.y; lds[swz(W+2)] = v.z; lds[swz(W+3)] = v.w;
    }
  }
  __syncthreads();

  const bool active = (t < nchunks);
  float m[CHUNK];
  float x1 = 0.f, x2 = 0.f, y1 = 0.f, y2 = 0.f;

  // Only the final FMA is on the loop-carried critical path.
  auto step = [&](float xn) -> float {
    float tt = fmaf(b2, x2, fmaf(b1, x1, b0 * xn));
    float u  = fmaf(-a2, y2, tt);
    float yn = fmaf(-a1, y1, u);
    x2 = x1; x1 = xn;
    y2 = y1; y1 = yn;
    return yn;
  };

  if (active) {
    const int base = t * CHUNK;  // warm-up start, in tile words
    // Warm-up: 64 steps, fetched 8 at a time (keeps VGPR low, batches LDS).
#pragma unroll
    for (int g = 0; g < WARM / 8; ++g) {
      float wv[8];
#pragma unroll
      for (int k = 0; k < 8; ++k) wv[k] = lds[swz(base + g * 8 + k)];
#pragma unroll
      for (int k = 0; k < 8; ++k) step(wv[k]);
    }
    // Main region into registers (read everything BEFORE the barrier).
#pragma unroll
    for (int k = 0; k < CHUNK; ++k) m[k] = lds[swz(base + WARM + k)];
  }
  __syncthreads();   // all LDS reads done before tile is overwritten

  if (active) {
#pragma unroll
    for (int k = 0; k < CHUNK; ++k) m[k] = step(m[k]);
    const int ob = WARM + t * CHUNK;
#pragma unroll
    for (int k = 0; k < CHUNK; ++k) lds[swz(ob + k)] = m[k];
  }
  __syncthreads();

  // ---- Coalesced float4 store of [S, S+words) from LDS.
  {
    float4* dst = reinterpret_cast<float4*>(yr + S);
    const int nf4 = words / 4;
    for (int i = t; i < nf4; i += 256) {
      int W = WARM + i * 4;
      float4 v;
      v.x = lds[swz(W)]; v.y = lds[swz(W+1)]; v.z = lds[swz(W+2)]; v.w = lds[swz(W+3)];
      dst[i] = v;
    }
  }
}

extern "C" void kernel_launch(void* const* d_in, const int* in_sizes, int n_in,
                              void* d_out, int out_size, void* d_ws, size_t ws_size,
                              hipStream_t stream) {
  const float* x = (const float*)d_in[0];
  float*       y = (float*)d_out;

  const double sample_rate = 16000.0, cutoff = 7500.0, Q = 0.707;
  double w0    = 2.0 * M_PI * cutoff / sample_rate;
  double alpha = sin(w0) / (2.0 * Q);
  double cw    = cos(w0);
  double a0    = 1.0 + alpha;
  float b0 = (float)(((1.0 - cw) * 0.5) / a0);
  float b1 = (float)((1.0 - cw) / a0);
  float b2 = b0;
  float a1 = (float)((-2.0 * cw) / a0);
  float a2 = (float)((1.0 - alpha) / a0);

  // 10000 chunks/row -> 40 blocks in x (39 full + 1 tail of 16 chunks); 64 rows.
  dim3 block(256);
  dim3 grid((NCHUNK + BLK_CHUNKS - 1) / BLK_CHUNKS, B_ROWS);
  hipLaunchKernelGGL(biquad_lds_kernel, grid, block, 0, stream,
                     x, y, b0, b1, b2, a1, a2);
}

// Round 6
// 33.357 us; speedup vs baseline: 2.6897x; 1.0889x over previous
//
#include <hip/hip_runtime.h>
#include <cmath>

#ifndef M_PI
#define M_PI 3.14159265358979323846
#endif

constexpr int T_LEN  = 320000;
constexpr int B_ROWS = 64;
constexpr int CHUNK  = 32;                       // samples per thread
constexpr int WARM   = 64;                       // pole decay 0.8704^64 ~ 1.4e-4
constexpr int NCHUNK = T_LEN / CHUNK;            // 10000 chunks per row
constexpr int BLK_CHUNKS = 256;                  // chunks per block
constexpr int BLK_SPAN   = BLK_CHUNKS * CHUNK;   // 8192 samples per block
constexpr int TILE_VECS  = (BLK_SPAN + WARM) / 4;  // 2064 float4 = 33 KB LDS
constexpr int WARM_VECS  = WARM / 4;             // 16
constexpr int VPT        = CHUNK / 4;            // 8 vectors per thread (main)

// Vector-granularity XOR swizzle (16B units). Bijective within every aligned
// 8-vector group. Lane-stride-8 accesses: V'%8 = k ^ ((l+c)&7) covers all 8
// bank-groups across 8 consecutive lanes -> ~2 lanes/bank (free, m136).
// Lane-contiguous accesses: permuted within 8-vector groups, still 1KB/instr.
__device__ __forceinline__ int swzv(int V) { return V ^ ((V >> 3) & 7); }

__global__ __launch_bounds__(256, 4) void biquad_lds_kernel(
    const float* __restrict__ x, float* __restrict__ y,
    float b0, float b1, float b2, float a1, float a2) {
  const int b   = blockIdx.x;
  const int row = blockIdx.y;
  const int t   = threadIdx.x;

  const int S       = b * BLK_SPAN;
  const int nchunks = min(BLK_CHUNKS, (T_LEN - S) / CHUNK);  // 256, or 16 (tail)
  const int nvecs   = nchunks * VPT;                          // data vectors

  const float* xr = x + (size_t)row * T_LEN;
  float*       yr = y + (size_t)row * T_LEN;

  __shared__ float4 lds4[TILE_VECS];

  // ---- Stage [S-WARM, S+span) as float4: coalesced global reads,
  // swizzled ds_write_b128. Block 0 zero-fills the warm region.
  if (b == 0) {
    if (t < WARM_VECS) lds4[swzv(t)] = make_float4(0.f, 0.f, 0.f, 0.f);
    const float4* src = reinterpret_cast<const float4*>(xr);
    for (int i = t; i < nvecs; i += 256) lds4[swzv(WARM_VECS + i)] = src[i];
  } else {
    const float4* src = reinterpret_cast<const float4*>(xr + S - WARM);
    const int nf4 = nvecs + WARM_VECS;
    for (int i = t; i < nf4; i += 256) lds4[swzv(i)] = src[i];
  }
  __syncthreads();

  const bool active = (t < nchunks);
  float4 m[VPT];
  float x1 = 0.f, x2 = 0.f, y1 = 0.f, y2 = 0.f;

  // Only the final FMA is on the loop-carried critical path.
  auto step = [&](float xn) -> float {
    float tt = fmaf(b2, x2, fmaf(b1, x1, b0 * xn));
    float u  = fmaf(-a2, y2, tt);
    float yn = fmaf(-a1, y1, u);
    x2 = x1; x1 = xn;
    y2 = y1; y1 = yn;
    return yn;
  };

  if (active) {
    const int vb = t * VPT;  // warm-up start vector for this thread
    // Warm-up: 64 steps, 4 ds_read_b128 in flight per group of 16 samples.
#pragma unroll
    for (int g = 0; g < WARM_VECS / 4; ++g) {
      float4 w0 = lds4[swzv(vb + g * 4 + 0)];
      float4 w1 = lds4[swzv(vb + g * 4 + 1)];
      float4 w2 = lds4[swzv(vb + g * 4 + 2)];
      float4 w3 = lds4[swzv(vb + g * 4 + 3)];
      step(w0.x); step(w0.y); step(w0.z); step(w0.w);
      step(w1.x); step(w1.y); step(w1.z); step(w1.w);
      step(w2.x); step(w2.y); step(w2.z); step(w2.w);
      step(w3.x); step(w3.y); step(w3.z); step(w3.w);
    }
    // Main region: 8 ds_read_b128 into registers, then pure-register compute.
#pragma unroll
    for (int k = 0; k < VPT; ++k) m[k] = lds4[swzv(vb + WARM_VECS + k)];
#pragma unroll
    for (int k = 0; k < VPT; ++k) {
      float4 v = m[k];
      m[k] = make_float4(step(v.x), step(v.y), step(v.z), step(v.w));
    }
  }
  __syncthreads();   // all warm/main reads done before tile is overwritten

  if (active) {
    const int ob = t * VPT + WARM_VECS;
#pragma unroll
    for (int k = 0; k < VPT; ++k) lds4[swzv(ob + k)] = m[k];
  }
  __syncthreads();

  // ---- Coalesced float4 store of [S, S+span) via swizzled ds_read_b128.
  {
    float4* dst = reinterpret_cast<float4*>(yr + S);
    for (int i = t; i < nvecs; i += 256) dst[i] = lds4[swzv(WARM_VECS + i)];
  }
}

extern "C" void kernel_launch(void* const* d_in, const int* in_sizes, int n_in,
                              void* d_out, int out_size, void* d_ws, size_t ws_size,
                              hipStream_t stream) {
  const float* x = (const float*)d_in[0];
  float*       y = (float*)d_out;

  const double sample_rate = 16000.0, cutoff = 7500.0, Q = 0.707;
  double w0    = 2.0 * M_PI * cutoff / sample_rate;
  double alpha = sin(w0) / (2.0 * Q);
  double cw    = cos(w0);
  double a0    = 1.0 + alpha;
  float b0 = (float)(((1.0 - cw) * 0.5) / a0);
  float b1 = (float)((1.0 - cw) / a0);
  float b2 = b0;
  float a1 = (float)((-2.0 * cw) / a0);
  float a2 = (float)((1.0 - alpha) / a0);

  dim3 block(256);
  dim3 grid((NCHUNK + BLK_CHUNKS - 1) / BLK_CHUNKS, B_ROWS);  // 40 x 64
  hipLaunchKernelGGL(biquad_lds_kernel, grid, block, 0, stream,
                     x, y, b0, b1, b2, a1, a2);
}